// Round 7
// baseline (738.512 us; speedup 1.0000x reference)
//
#include <hip/hip_runtime.h>

#define NB 16
#define NH 128
#define NW 128
#define NC 64   // in channels
#define NO 64   // out channels
#define NM 16   // modes

// workspace float offsets
#define OFF_AR   0                          // 2097152: T1_re[b][ky][h][i]
#define OFF_AI   (OFF_AR + 2097152)
#define OFF_XR   (OFF_AI + 2097152)         // 262144: X_re[kk][b][i]
#define OFF_XI   (OFF_XR + 262144)
#define OFF_OR   (OFF_XI + 262144)          // 262144: O_re[kk][b][o]
#define OFF_OI   (OFF_OR + 262144)
#define OFF_BAR  (OFF_OI + 262144)          // barrier counters (zeroed via hipMemsetAsync)

#define R2F 0.70710678118654752f

// cos(pi*t/64) for t=0..32
constexpr float CQ[33] = {
  1.000000000f, 0.998795456f, 0.995184727f, 0.989176510f,
  0.980785280f, 0.970031253f, 0.956940336f, 0.941544065f,
  0.923879533f, 0.903989293f, 0.881921264f, 0.857728610f,
  0.831469612f, 0.803207531f, 0.773010453f, 0.740951125f,
  0.707106781f, 0.671558955f, 0.634393284f, 0.595699304f,
  0.555570233f, 0.514102744f, 0.471396737f, 0.427555093f,
  0.382683432f, 0.336889853f, 0.290284677f, 0.242980180f,
  0.195090322f, 0.146730474f, 0.098017140f, 0.049067674f,
  0.000000000f };

__host__ __device__ constexpr float twcos(int t) {   // cos(2*pi*t/128)
  t &= 127;
  return (t <= 32) ? CQ[t] : (t < 64) ? -CQ[64 - t] : (t <= 96) ? -CQ[t - 64] : CQ[128 - t];
}
__host__ __device__ constexpr float twsin(int t) { return twcos(t + 96); }

// ---- template twiddle ops (compile-time exponent; folding guaranteed) ----
template<int T>
__device__ __forceinline__ void caccN_t(float gr, float gi, float& ar, float& ai) {
  constexpr int t = T & 127;
  if constexpr (t == 0)       { ar += gr; ai += gi; }
  else if constexpr (t == 64) { ar -= gr; ai -= gi; }
  else if constexpr (t == 32) { ar += gi; ai -= gr; }
  else if constexpr (t == 96) { ar -= gi; ai += gr; }
  else {
    constexpr float c = twcos(t), s = twsin(t);
    ar = fmaf(gr, c, fmaf(gi, s, ar));
    ai = fmaf(gi, c, fmaf(-gr, s, ai));
  }
}
template<int T>
__device__ __forceinline__ void caccP_t(float gr, float gi, float& ar, float& ai) {
  constexpr int t = T & 127;
  if constexpr (t == 0)       { ar += gr; ai += gi; }
  else if constexpr (t == 64) { ar -= gr; ai -= gi; }
  else if constexpr (t == 32) { ar -= gi; ai += gr; }
  else if constexpr (t == 96) { ar += gi; ai -= gr; }
  else {
    constexpr float c = twcos(t), s = twsin(t);
    ar = fmaf(gr, c, fmaf(-gi, s, ar));
    ai = fmaf(gi, c, fmaf(gr, s, ai));
  }
}
template<int T>
__device__ __forceinline__ void crotN_t(float& ar, float& ai) {
  constexpr int t = T & 127;
  if constexpr (t == 0) {}
  else if constexpr (t == 64) { ar = -ar; ai = -ai; }
  else if constexpr (t == 32) { const float r = ar; ar = ai; ai = -r; }
  else if constexpr (t == 96) { const float r = ar; ar = -ai; ai = r; }
  else {
    constexpr float c = twcos(t), s = twsin(t);
    const float r = ar;
    ar = fmaf(r, c, ai * s);
    ai = fmaf(ai, c, -r * s);
  }
}
template<int T>
__device__ __forceinline__ void crotP_t(float& ar, float& ai) {
  constexpr int t = T & 127;
  if constexpr (t == 0) {}
  else if constexpr (t == 64) { ar = -ar; ai = -ai; }
  else if constexpr (t == 32) { const float r = ar; ar = -ai; ai = r; }
  else if constexpr (t == 96) { const float r = ar; ar = ai;  ai = -r; }
  else {
    constexpr float c = twcos(t), s = twsin(t);
    const float r = ar;
    ar = fmaf(r, c, -(ai * s));
    ai = fmaf(ai, c, r * s);
  }
}

// ---------------- device-scope grid barrier (all 1024 blocks resident by construction)
__device__ __forceinline__ void gbar(unsigned* bar, unsigned target) {
  __syncthreads();
  if (threadIdx.x == 0) {
    __threadfence();
    __hip_atomic_fetch_add(bar, 1u, __ATOMIC_RELEASE, __HIP_MEMORY_SCOPE_AGENT);
    while (__hip_atomic_load(bar, __ATOMIC_ACQUIRE, __HIP_MEMORY_SCOPE_AGENT) < target) {
      __builtin_amdgcn_s_sleep(8);
    }
    __threadfence();
  }
  __syncthreads();
}

// ---------------------------------------------------------------- P1 helpers (k1, proven R5)
template<int K>
__device__ __forceinline__ void k1_zeroT(float (&Tr)[16], float (&Ti)[16]) {
  if constexpr (K < 16) { Tr[K] = 0.f; Ti[K] = 0.f; k1_zeroT<K + 1>(Tr, Ti); }
}
template<int K, int P0>
__device__ __forceinline__ void k1_initR(float (&Rr)[16], float (&Ri)[16]) {
  if constexpr (K < 16) {
    constexpr int t = (K * P0) & 127;
    Rr[K] = twcos(t);
    Ri[K] = -twsin(t);
    k1_initR<K + 1, P0>(Rr, Ri);
  }
}
template<int W1>
__device__ __forceinline__ void k1_ld8(const float* xp, int w0, float (&v)[8]) {
  if constexpr (W1 < 8) {
    v[W1] = xp[(W1 * 16 + w0) * NC];
    k1_ld8<W1 + 1>(xp, w0, v);
  }
}
template<int W1>
__device__ __forceinline__ void k1_cp8(float (&a)[8], const float (&b)[8]) {
  if constexpr (W1 < 8) { a[W1] = b[W1]; k1_cp8<W1 + 1>(a, b); }
}
template<int KY>
__device__ __forceinline__ void k1_acc(float g0r, float g4r, float g1r, float g1i,
                                       float g2r, float g2i, float g3r, float g3i,
                                       float (&Tr)[16], float (&Ti)[16],
                                       float (&Rr)[16], float (&Ri)[16]) {
  if constexpr (KY < 16) {
    constexpr int p = KY & 7;
    if constexpr (p == 0 || p == 4) {
      const float gr = (p == 0) ? g0r : g4r;
      Tr[KY] = fmaf(gr, Rr[KY], Tr[KY]);
      Ti[KY] = fmaf(gr, Ri[KY], Ti[KY]);
    } else {
      float gr, gi;
      if constexpr (p == 1)      { gr = g1r; gi = g1i; }
      else if constexpr (p == 2) { gr = g2r; gi = g2i; }
      else if constexpr (p == 3) { gr = g3r; gi = g3i; }
      else if constexpr (p == 5) { gr = g3r; gi = -g3i; }
      else if constexpr (p == 6) { gr = g2r; gi = -g2i; }
      else                       { gr = g1r; gi = -g1i; }
      Tr[KY] = fmaf(gr, Rr[KY], fmaf(-gi, Ri[KY], Tr[KY]));
      Ti[KY] = fmaf(gr, Ri[KY], fmaf( gi, Rr[KY], Ti[KY]));
    }
    crotN_t<KY>(Rr[KY], Ri[KY]);
    k1_acc<KY + 1>(g0r, g4r, g1r, g1i, g2r, g2i, g3r, g3i, Tr, Ti, Rr, Ri);
  }
}
template<int K>
__device__ __forceinline__ void k1_ldswr(float* p, const float (&Tr)[16], const float (&Ti)[16]) {
  if constexpr (K < 16) {
    p[K * 64]        = Tr[K];
    p[(16 + K) * 64] = Ti[K];
    k1_ldswr<K + 1>(p, Tr, Ti);
  }
}
template<int K>
__device__ __forceinline__ void k1_ldsadd(const float* p, float (&Tr)[16], float (&Ti)[16]) {
  if constexpr (K < 16) {
    Tr[K] += p[K * 64];
    Ti[K] += p[(16 + K) * 64];
    k1_ldsadd<K + 1>(p, Tr, Ti);
  }
}
template<int KY>
__device__ __forceinline__ void k1_store(float* t1r, float* t1i,
                                         const float (&Tr)[16], const float (&Ti)[16]) {
  if constexpr (KY < 16) {
    t1r[(size_t)KY * (NH * NC)] = Tr[KY];
    t1i[(size_t)KY * (NH * NC)] = Ti[KY];
    k1_store<KY + 1>(t1r, t1i, Tr, Ti);
  }
}

// ---------------------------------------------------------------- P2 helpers (k2a, 4-wave form)
template<int K>
__device__ __forceinline__ void k2a_zero(float (&Ar)[16], float (&Ai)[16]) {
  if constexpr (K < 16) { Ar[K] = 0.f; Ai[K] = 0.f; k2a_zero<K + 1>(Ar, Ai); }
}
template<int KX, int J>
__device__ __forceinline__ void k2a_kx(float re, float im, float (&Ar)[16], float (&Ai)[16]) {
  if constexpr (KX < 16) {
    caccN_t<(KX * J) & 127>(re, im, Ar[KX], Ai[KX]);
    k2a_kx<KX + 1, J>(re, im, Ar, Ai);
  }
}
template<int J>
__device__ __forceinline__ void k2a_j32(const float* pr, const float* pi,
                                        float (&Ar)[16], float (&Ai)[16]) {
  if constexpr (J < 32) {
    const float re = pr[J * NC];
    const float im = pi[J * NC];
    k2a_kx<0, J>(re, im, Ar, Ai);
    k2a_j32<J + 1>(pr, pi, Ar, Ai);
  }
}
template<int G, int KX>
__device__ __forceinline__ void k2a_rotg32(float (&Ar)[16], float (&Ai)[16]) {
  if constexpr (KX < 16) {
    crotN_t<(32 * KX * G) & 127>(Ar[KX], Ai[KX]);   // multiples of 32 -> free sign/swaps
    k2a_rotg32<G, KX + 1>(Ar, Ai);
  }
}
template<int KX>
__device__ __forceinline__ void k2a_ldsw(float* pr, float* pi,
                                         const float (&Ar)[16], const float (&Ai)[16]) {
  if constexpr (KX < 16) {
    pr[KX * 64] = Ar[KX]; pi[KX * 64] = Ai[KX];
    k2a_ldsw<KX + 1>(pr, pi, Ar, Ai);
  }
}

// ---------------------------------------------------------------- P4 helpers (k35, proven R6)
template<int K>
__device__ __forceinline__ void k35_zero(float (&Tr)[16], float (&Ti)[16]) {
  if constexpr (K < 16) { Tr[K] = 0.f; Ti[K] = 0.f; k35_zero<K + 1>(Tr, Ti); }
}
template<int KY, int KYEND>
__device__ __forceinline__ void k35_ld(const float* orp, const float* oip,
                                       float (&orv)[16], float (&oiv)[16]) {
  if constexpr (KY < KYEND) {
    orv[KY] = orp[KY * (NB * NO)];
    oiv[KY] = oip[KY * (NB * NO)];
    k35_ld<KY + 1, KYEND>(orp, oip, orv, oiv);
  }
}
template<int KY, int KYEND>
__device__ __forceinline__ void k35_acc(const float (&orv)[16], const float (&oiv)[16],
                                        float Rr, float Ri,
                                        float (&Tr)[16], float (&Ti)[16]) {
  if constexpr (KY < KYEND) {
    Tr[KY] = fmaf(orv[KY], Rr, fmaf(-oiv[KY], Ri, Tr[KY]));
    Ti[KY] = fmaf(orv[KY], Ri, fmaf( oiv[KY], Rr, Ti[KY]));
    k35_acc<KY + 1, KYEND>(orv, oiv, Rr, Ri, Tr, Ti);
  }
}
template<int K>
__device__ __forceinline__ void k35_scale(float (&Tr)[16], float (&Ti)[16]) {
  if constexpr (K < 16) {
    constexpr float sc = (K == 0 ? 1.0f : 2.0f) * (1.0f / 16384.0f);
    Tr[K] *= sc; Ti[K] *= sc;
    k35_scale<K + 1>(Tr, Ti);
  }
}
template<int KY, int W0>
__device__ __forceinline__ void k5_u(const float (&Tr)[16], const float (&Ti)[16],
                                     float (&Ur)[8], float (&Ui)[8]) {
  if constexpr (KY < 16) {
    caccP_t<(KY * W0) & 127>(Tr[KY], Ti[KY], Ur[KY & 7], Ui[KY & 7]);
    k5_u<KY + 1, W0>(Tr, Ti, Ur, Ui);
  }
}
template<int P>
__device__ __forceinline__ void k5_uzero(float (&Ur)[8], float (&Ui)[8]) {
  if constexpr (P < 8) { Ur[P] = 0.f; Ui[P] = 0.f; k5_uzero<P + 1>(Ur, Ui); }
}
template<int W0, int W0END>
__device__ __forceinline__ void k5_w0(const float (&Tr)[16], const float (&Ti)[16],
                                      float* yp) {
  if constexpr (W0 < W0END) {
    float Ur[8], Ui[8];
    k5_uzero<0>(Ur, Ui);
    k5_u<0, W0>(Tr, Ti, Ur, Ui);
    const float A  = Ur[0], B = Ur[4];
    const float Cr = Ur[2] + Ur[6], Ci = Ui[2] - Ui[6];
    const float Dr = Ur[1] + Ur[7], Di = Ui[1] - Ui[7];
    const float Er = Ur[3] + Ur[5], Ei = Ui[3] - Ui[5];
    const float P = A + B, M = A - B;
    const float DE = Dr + Er, IE = Di - Ei;
    const float X1 = R2F * ((Dr - Di) - (Er + Ei));
    const float X3 = R2F * ((Dr + Di) - (Er - Ei));
    const float MmC = M - Ci, MpC = M + Ci, PpC = P + Cr, PmC = P - Cr;
    yp[(0 * 16 + W0) * NO] = PpC + DE;
    yp[(4 * 16 + W0) * NO] = PpC - DE;
    yp[(2 * 16 + W0) * NO] = PmC - IE;
    yp[(6 * 16 + W0) * NO] = PmC + IE;
    yp[(1 * 16 + W0) * NO] = MmC + X1;
    yp[(5 * 16 + W0) * NO] = MmC - X1;
    yp[(3 * 16 + W0) * NO] = MpC - X3;
    yp[(7 * 16 + W0) * NO] = MpC + X3;
    k5_w0<W0 + 1, W0END>(Tr, Ti, yp);
  }
}

// ================================================================ fused mega-kernel
// 1024 blocks x 256 threads, 4 blocks/CU (32 KB LDS, VGPR<=128) -> all resident.
__global__ __launch_bounds__(256, 4) void k_fused(const float* __restrict__ x,
                                                  const float* __restrict__ wre,
                                                  const float* __restrict__ wim,
                                                  float* __restrict__ t1r,
                                                  float* __restrict__ t1i,
                                                  float* __restrict__ xre,
                                                  float* __restrict__ xim,
                                                  float* __restrict__ ore,
                                                  float* __restrict__ oim,
                                                  float* __restrict__ y,
                                                  unsigned* __restrict__ bar) {
  __shared__ __align__(16) float smem[8192];   // 32 KB, reused per phase
  const int blk  = blockIdx.x;
  const int tid  = threadIdx.x;
  const int wv   = tid >> 6;
  const int lane = tid & 63;

  // ---------------- P1: w-DFT  (2 slabs/block, 2 waves/slab)
  {
    const int sq   = wv >> 1;
    const int half = wv & 1;
    const int slab = blk * 2 + sq;              // b*128 + h
    const float* xp = x + (size_t)slab * (NW * NC) + lane;
    float Tr[16], Ti[16], Rr[16], Ri[16];
    k1_zeroT<0>(Tr, Ti);
    if (half == 0) k1_initR<0, 0>(Rr, Ri);
    else           k1_initR<0, 8>(Rr, Ri);
    float xv[8], nx[8];
    k1_ld8<0>(xp, half * 8, xv);
    for (int it = 0; it < 8; ++it) {
      const int w0 = half * 8 + it;
      if (it < 7) k1_ld8<0>(xp, w0 + 1, nx);
      const float s0 = xv[0] + xv[4], d0 = xv[0] - xv[4];
      const float s1 = xv[1] + xv[5], d1 = xv[1] - xv[5];
      const float s2 = xv[2] + xv[6], d2 = xv[2] - xv[6];
      const float s3 = xv[3] + xv[7], d3 = xv[3] - xv[7];
      const float e0 = s0 + s2, e1 = s0 - s2;
      const float f0 = s1 + s3, f1 = s1 - s3;
      const float u = R2F * (d1 - d3), v = R2F * (d1 + d3);
      const float g0r = e0 + f0;
      const float g4r = e0 - f0;
      const float g1r = d0 + u, g1i = -(d2 + v);
      const float g2r = e1,     g2i = -f1;
      const float g3r = d0 - u, g3i = d2 - v;
      k1_acc<0>(g0r, g4r, g1r, g1i, g2r, g2i, g3r, g3i, Tr, Ti, Rr, Ri);
      k1_cp8<0>(xv, nx);
    }
    float* lp = &smem[sq * 2048 + lane];        // [2][32][64]
    if (half) k1_ldswr<0>(lp, Tr, Ti);
    __syncthreads();
    if (!half) {
      k1_ldsadd<0>(lp, Tr, Ti);
      const int b = slab >> 7, h = slab & 127;
      const size_t base = ((size_t)b * 2048 + h) * NC + lane;
      k1_store<0>(t1r + base, t1i + base, Tr, Ti);
    }
  }
  gbar(bar, 1024);

  // ---------------- P2: h-DFT  (blocks 0..255; 4 waves x 32 h)
  if (blk < 256) {
    const int bk = blk;                         // b*16 + ky
    const float* pr = t1r + (size_t)bk * (NH * NC) + (wv * 32) * NC + lane;
    const float* pi = t1i + (size_t)bk * (NH * NC) + (wv * 32) * NC + lane;
    float Ar[16], Ai[16];
    k2a_zero<0>(Ar, Ai);
    k2a_j32<0>(pr, pi, Ar, Ai);
    switch (wv) {                               // post-rotate by e^{-2 pi i kx*32*wv/128}
      case 1: k2a_rotg32<1, 0>(Ar, Ai); break;
      case 2: k2a_rotg32<2, 0>(Ar, Ai); break;
      case 3: k2a_rotg32<3, 0>(Ar, Ai); break;
      default: break;
    }
    float* wpr = &smem[wv * 1024 + lane];       // lpr[4][16][64]
    float* wpi = wpr + 4096;                    // lpi[4][16][64]
    k2a_ldsw<0>(wpr, wpi, Ar, Ai);
    __syncthreads();
    const int b = bk >> 4, ky = bk & 15;
#pragma unroll
    for (int p = 0; p < 4; ++p) {
      const int kx = wv * 4 + p;
      float sr = 0.f, si = 0.f;
#pragma unroll
      for (int q = 0; q < 4; ++q) {
        sr += smem[q * 1024 + kx * 64 + lane];
        si += smem[4096 + q * 1024 + kx * 64 + lane];
      }
      const size_t idx = (size_t)(kx * NM + ky) * (NB * NC) + b * NC + lane;
      xre[idx] = sr;
      xim[idx] = si;
    }
  }
  gbar(bar, 2048);

  // ---------------- P3: channel mix  (blocks 0..255; W staged in two i-halves)
  if (blk < 256) {
    const int kk = blk;
    float* lwr = smem;                          // [32][64]
    float* lwi = smem + 2048;
    float* lxr = smem + 4096;                   // [16][64]
    float* lxi = smem + 5120;
    for (int t = tid; t < 1024; t += 256) {
      lxr[t] = xre[(size_t)kk * 1024 + t];
      lxi[t] = xim[(size_t)kk * 1024 + t];
    }
    for (int t = tid; t < 2048; t += 256) {     // i in [0,32): element (i*64+o) = t
      lwr[t] = wre[(size_t)t * 256 + kk];
      lwi[t] = wim[(size_t)t * 256 + kk];
    }
    __syncthreads();
    const int o  = lane;
    const int bq = wv;                          // 4 b per wave
    float accr[4] = {0, 0, 0, 0}, acci[4] = {0, 0, 0, 0};
    for (int iq = 0; iq < 8; ++iq) {
      float xrv[4][4], xiv[4][4];
#pragma unroll
      for (int p = 0; p < 4; ++p) {
        const int b = bq * 4 + p;
        float4 vr = ((const float4*)lxr)[b * 16 + iq];
        float4 vi = ((const float4*)lxi)[b * 16 + iq];
        xrv[p][0] = vr.x; xrv[p][1] = vr.y; xrv[p][2] = vr.z; xrv[p][3] = vr.w;
        xiv[p][0] = vi.x; xiv[p][1] = vi.y; xiv[p][2] = vi.z; xiv[p][3] = vi.w;
      }
#pragma unroll
      for (int j = 0; j < 4; ++j) {
        const int i2 = iq * 4 + j;              // local i (0..31)
        const float wr = lwr[i2 * 64 + o];
        const float wi = lwi[i2 * 64 + o];
#pragma unroll
        for (int p = 0; p < 4; ++p) {
          accr[p] = fmaf(xrv[p][j], wr, fmaf(-xiv[p][j], wi, accr[p]));
          acci[p] = fmaf(xrv[p][j], wi, fmaf(xiv[p][j], wr, acci[p]));
        }
      }
    }
    __syncthreads();
    for (int t = tid; t < 2048; t += 256) {     // i in [32,64): element = t + 2048
      lwr[t] = wre[(size_t)(t + 2048) * 256 + kk];
      lwi[t] = wim[(size_t)(t + 2048) * 256 + kk];
    }
    __syncthreads();
    for (int iq = 8; iq < 16; ++iq) {
      float xrv[4][4], xiv[4][4];
#pragma unroll
      for (int p = 0; p < 4; ++p) {
        const int b = bq * 4 + p;
        float4 vr = ((const float4*)lxr)[b * 16 + iq];
        float4 vi = ((const float4*)lxi)[b * 16 + iq];
        xrv[p][0] = vr.x; xrv[p][1] = vr.y; xrv[p][2] = vr.z; xrv[p][3] = vr.w;
        xiv[p][0] = vi.x; xiv[p][1] = vi.y; xiv[p][2] = vi.z; xiv[p][3] = vi.w;
      }
#pragma unroll
      for (int j = 0; j < 4; ++j) {
        const int i2 = (iq - 8) * 4 + j;        // local slot in half B
        const float wr = lwr[i2 * 64 + o];
        const float wi = lwi[i2 * 64 + o];
#pragma unroll
        for (int p = 0; p < 4; ++p) {
          accr[p] = fmaf(xrv[p][j], wr, fmaf(-xiv[p][j], wi, accr[p]));
          acci[p] = fmaf(xrv[p][j], wi, fmaf(xiv[p][j], wr, acci[p]));
        }
      }
    }
#pragma unroll
    for (int p = 0; p < 4; ++p) {
      const int b = bq * 4 + p;
      ore[(size_t)kk * 1024 + b * 64 + o] = accr[p];
      oim[(size_t)kk * 1024 + b * 64 + o] = acci[p];
    }
  }
  gbar(bar, 3072);

  // ---------------- P4: fused h-inverse + w-inverse  (2 slabs/block, 2 waves/slab)
  {
    const int sq   = wv >> 1;
    const int kh   = wv & 1;                    // kx half
    const int slab = blk * 2 + sq;              // b*128 + h
    const int b = slab >> 7, h = slab & 127;
    float c1 = 1.f, s1 = 0.f;                   // e^{+2 pi i h/128}
    if (h & 1)  crotP_t<1>(c1, s1);
    if (h & 2)  crotP_t<2>(c1, s1);
    if (h & 4)  crotP_t<4>(c1, s1);
    if (h & 8)  crotP_t<8>(c1, s1);
    if (h & 16) crotP_t<16>(c1, s1);
    if (h & 32) crotP_t<32>(c1, s1);
    if (h & 64) crotP_t<64>(c1, s1);
    float Rr = 1.f, Ri = 0.f;                   // e^{+2 pi i (8 kh) h/128}
    if (kh) {
      if (h & 1) crotP_t<8>(Rr, Ri);
      if (h & 2) crotP_t<16>(Rr, Ri);
      if (h & 4) crotP_t<32>(Rr, Ri);
      if (h & 8) crotP_t<64>(Rr, Ri);
    }
    float Tr[16], Ti[16];
    k35_zero<0>(Tr, Ti);
    const float* orp = ore + (size_t)(kh * 8) * (NM * NB * NO) + b * NO + lane;
    const float* oip = oim + (size_t)(kh * 8) * (NM * NB * NO) + b * NO + lane;
    for (int kx = 0; kx < 8; ++kx) {
      float orv[16], oiv[16];
      k35_ld<0, 8>(orp, oip, orv, oiv);
      k35_acc<0, 8>(orv, oiv, Rr, Ri, Tr, Ti);
      k35_ld<8, 16>(orp, oip, orv, oiv);
      k35_acc<8, 16>(orv, oiv, Rr, Ri, Tr, Ti);
      const float nr = fmaf(Rr, c1, -(Ri * s1));
      const float ni = fmaf(Rr, s1, Ri * c1);
      Rr = nr; Ri = ni;
      orp += NM * NB * NO;
      oip += NM * NB * NO;
    }
    float* wp = &smem[(sq * 2 + kh) * 2048 + lane];   // [2][2][32][64]
    k1_ldswr<0>(wp, Tr, Ti);
    __syncthreads();
    const float* rp = &smem[(sq * 2 + (kh ^ 1)) * 2048 + lane];
    k1_ldsadd<0>(rp, Tr, Ti);
    k35_scale<0>(Tr, Ti);
    float* yp = y + (size_t)slab * (NW * NO) + lane;
    if (kh == 0) k5_w0<0, 8>(Tr, Ti, yp);
    else         k5_w0<8, 16>(Tr, Ti, yp);
  }
}

extern "C" void kernel_launch(void* const* d_in, const int* in_sizes, int n_in,
                              void* d_out, int out_size, void* d_ws, size_t ws_size,
                              hipStream_t stream) {
  const float* x   = (const float*)d_in[0];
  const float* wre = (const float*)d_in[1];
  const float* wim = (const float*)d_in[2];
  float* ws  = (float*)d_ws;
  float* ar  = ws + OFF_AR;
  float* ai  = ws + OFF_AI;
  float* xr  = ws + OFF_XR;
  float* xi  = ws + OFF_XI;
  float* orr = ws + OFF_OR;
  float* oii = ws + OFF_OI;
  unsigned* bar = (unsigned*)(ws + OFF_BAR);
  float* y   = (float*)d_out;

  hipMemsetAsync(bar, 0, 256, stream);   // zero barrier counters (captured in graph)
  k_fused<<<1024, 256, 0, stream>>>(x, wre, wim, ar, ai, xr, xi, orr, oii, y, bar);
}